// Round 5
// baseline (167.476 us; speedup 1.0000x reference)
//
#include <hip/hip_runtime.h>
#include <hip/hip_bf16.h>
#include <hip/hip_cooperative_groups.h>
#include <math.h>

namespace cg = cooperative_groups;

#define NB 16
#define NG 32
#define NM 320
#define NN 960      // 3 * NM
#define NA 3
#define NCH 85
#define NC 80
#define NK 20

#define GRID 512
#define BLK  256
#define NWAVE (GRID * (BLK / 64))   // 2048 waves

// ---------------- DPP wave-reduce helpers (gfx9 lineage: row_shr + row_bcast) ----------
template<int CTRL>
__device__ __forceinline__ unsigned long long dpp_u64_self(unsigned long long x) {
    int lo = (int)(unsigned)(x & 0xFFFFFFFFull);
    int hi = (int)(unsigned)(x >> 32);
    int lo2 = __builtin_amdgcn_update_dpp(lo, lo, CTRL, 0xF, 0xF, false);
    int hi2 = __builtin_amdgcn_update_dpp(hi, hi, CTRL, 0xF, 0xF, false);
    return ((unsigned long long)(unsigned)hi2 << 32) | (unsigned)lo2;
}

// max-reduce of u64 keys; result valid in lane 63
__device__ __forceinline__ unsigned long long dpp_max_u64(unsigned long long x) {
    unsigned long long o;
    o = dpp_u64_self<0x111>(x); x = (o > x) ? o : x;   // row_shr:1
    o = dpp_u64_self<0x112>(x); x = (o > x) ? o : x;   // row_shr:2
    o = dpp_u64_self<0x114>(x); x = (o > x) ? o : x;   // row_shr:4
    o = dpp_u64_self<0x118>(x); x = (o > x) ? o : x;   // row_shr:8
    o = dpp_u64_self<0x142>(x); x = (o > x) ? o : x;   // row_bcast:15
    o = dpp_u64_self<0x143>(x); x = (o > x) ? o : x;   // row_bcast:31
    return x;
}

__device__ __forceinline__ unsigned long long dpp_min_u64(unsigned long long x) {
    unsigned long long o;
    o = dpp_u64_self<0x111>(x); x = (o < x) ? o : x;
    o = dpp_u64_self<0x112>(x); x = (o < x) ? o : x;
    o = dpp_u64_self<0x114>(x); x = (o < x) ? o : x;
    o = dpp_u64_self<0x118>(x); x = (o < x) ? o : x;
    o = dpp_u64_self<0x142>(x); x = (o < x) ? o : x;
    o = dpp_u64_self<0x143>(x); x = (o < x) ? o : x;
    return x;
}

// f64 add-reduce (bound_ctrl=1: invalid lanes contribute +0.0); result valid in lane 63
template<int CTRL>
__device__ __forceinline__ double dpp_f64_zero(double x) {
    long long b = __double_as_longlong(x);
    int lo = (int)(unsigned)((unsigned long long)b & 0xFFFFFFFFull);
    int hi = (int)(unsigned)((unsigned long long)b >> 32);
    int lo2 = __builtin_amdgcn_update_dpp(0, lo, CTRL, 0xF, 0xF, true);
    int hi2 = __builtin_amdgcn_update_dpp(0, hi, CTRL, 0xF, 0xF, true);
    unsigned long long r = ((unsigned long long)(unsigned)hi2 << 32) | (unsigned)lo2;
    return __longlong_as_double((long long)r);
}

__device__ __forceinline__ double dpp_sum_f64(double x) {
    x += dpp_f64_zero<0x111>(x);
    x += dpp_f64_zero<0x112>(x);
    x += dpp_f64_zero<0x114>(x);
    x += dpp_f64_zero<0x118>(x);
    x += dpp_f64_zero<0x142>(x);
    x += dpp_f64_zero<0x143>(x);
    return x;   // lane 63 holds the total
}

struct KParams {
    const float *p0, *p1, *p2, *tgt;
    const int *a0, *gj0, *gi0, *a1, *gj1, *gi1, *a2, *gj2, *gi2;
    int *coff, *clvl;
    float *pobj, *parea, *pbox;
    double *Ssum;
    float *ocost;
    unsigned char *match0;
    float *om, *ofg, *omg;
};

__global__ __launch_bounds__(BLK, 2) void k_fused(KParams P)
{
    cg::grid_group grid = cg::this_grid();
    int lane = (int)threadIdx.x & 63;
    int gw = (int)blockIdx.x * (BLK / 64) + ((int)threadIdx.x >> 6);   // global wave id

    // ================= P1: per-candidate prep (one wave per candidate) =================
    for (int wid = gw; wid < NB * NN; wid += NWAVE) {
        int b = wid / NN, n = wid % NN;
        int lvl = (n < NM) ? 0 : ((n < 2 * NM) ? 1 : 2);
        int m = n - lvl * NM;

        const int* pa = (lvl == 0) ? P.a0 : ((lvl == 1) ? P.a1 : P.a2);
        const int* pj = (lvl == 0) ? P.gj0 : ((lvl == 1) ? P.gj1 : P.gj2);
        const int* pi = (lvl == 0) ? P.gi0 : ((lvl == 1) ? P.gi1 : P.gi2);
        const float* pr = (lvl == 0) ? P.p0 : ((lvl == 1) ? P.p1 : P.p2);
        int h = (lvl == 0) ? 80 : ((lvl == 1) ? 40 : 20);
        float s = (lvl == 0) ? 8.0f : ((lvl == 1) ? 16.0f : 32.0f);

        int aa = pa[b * NM + m];
        int jj = pj[b * NM + m];
        int ii = pi[b * NM + m];
        int off = (((b * NA + aa) * h + jj) * h + ii) * NCH;
        const float* c = pr + off;

        float po = c[4];
        double S = 0.0;
        for (int cc = lane; cc < NC; cc += 64) {
            float pc = c[5 + cc];
            float y = sqrtf(pc * po);
            float z = logf(y / (1.0f - y));
            float sp = fmaxf(z, 0.0f) + log1pf(expf(-fabsf(z)));
            S += (double)sp;
        }
        S = dpp_sum_f64(S);   // valid in lane 63

        if (lane == 63) {
            float cx = c[0] * s, cy = c[1] * s, w = c[2] * s, hh = c[3] * s;
            float x1 = cx - w * 0.5f, y1 = cy - hh * 0.5f;
            float x2 = cx + w * 0.5f, y2 = cy + hh * 0.5f;

            P.coff[wid] = off;
            P.clvl[wid] = lvl;
            P.pobj[wid] = po;
            P.parea[wid] = (x2 - x1) * (y2 - y1);
            P.pbox[wid * 4 + 0] = x1;
            P.pbox[wid * 4 + 1] = y1;
            P.pbox[wid * 4 + 2] = x2;
            P.pbox[wid * 4 + 3] = y2;
            P.Ssum[wid] = S;
        }
    }

    grid.sync();

    // ================= P2: one wave per (b, g) row =================
    if (gw < NB * NG) {
        int bg = gw;
        int b = bg / NG;
        int t = lane;

        const float* tg = P.tgt + bg * 6;
        int cls = (int)tg[1];
        float gcx = tg[2] * 640.0f, gcy = tg[3] * 640.0f;
        float gw_ = tg[4] * 640.0f, gh = tg[5] * 640.0f;
        float gx1 = gcx - gw_ * 0.5f, gy1 = gcy - gh * 0.5f;
        float gx2 = gcx + gw_ * 0.5f, gy2 = gcy + gh * 0.5f;
        float ga = (gx2 - gx1) * (gy2 - gy1);

        float cl[15], io[15];
        #pragma unroll
        for (int j = 0; j < 15; ++j) {
            int n = j * 64 + t;
            int idx = b * NN + n;
            int lvl = P.clvl[idx];
            const float* pr = (lvl == 0) ? P.p0 : ((lvl == 1) ? P.p1 : P.p2);
            float pc = pr[P.coff[idx] + 5 + cls];
            float po = P.pobj[idx];
            float y = sqrtf(pc * po);
            float z = logf(y / (1.0f - y));
            float clsl = (float)(P.Ssum[idx] - (double)z);

            const float* pb = P.pbox + idx * 4;
            float lx = fmaxf(gx1, pb[0]), ly = fmaxf(gy1, pb[1]);
            float rx = fminf(gx2, pb[2]), ry = fminf(gy2, pb[3]);
            float wx = fmaxf(rx - lx, 0.0f), wy = fmaxf(ry - ly, 0.0f);
            float inter = wx * wy;
            float iou = inter / (ga + P.parea[idx] - inter);
            float il = -logf(iou + 1e-5f);
            float cst = clsl + 3.0f * il;

            cl[j] = cst;
            io[j] = iou;
            P.ocost[bg * NN + n] = cst;
        }

        // ---- dk: sum of top-20 iou. iou >= 0 so float bits are order-monotonic.
        double ssum = 0.0;
        for (int k = 0; k < NK; ++k) {
            float bv = io[0]; int bj = 0;
            #pragma unroll
            for (int j = 1; j < 15; ++j) {
                if (io[j] > bv) { bv = io[j]; bj = j; }
            }
            unsigned long long key =
                ((unsigned long long)__float_as_uint(bv) << 32) | (unsigned)(~(unsigned)(bj * 64 + t));
            key = dpp_max_u64(key);
            unsigned lo = (unsigned)__builtin_amdgcn_readlane((int)(unsigned)(key & 0xFFFFFFFFull), 63);
            unsigned hi = (unsigned)__builtin_amdgcn_readlane((int)(unsigned)(key >> 32), 63);
            float mval = __uint_as_float(hi);
            int mn = (int)(~lo);
            ssum += (double)mval;
            bool win = ((mn & 63) == t);
            int slot = mn >> 6;
            #pragma unroll
            for (int j = 0; j < 15; ++j) io[j] = (win && slot == j) ? -2.0f : io[j];
        }
        int dk = (int)((float)ssum);
        if (dk < 1) dk = 1;
        if (dk > NK) dk = NK;

        // ---- select dk smallest costs (cost > 0, bits monotonic), tie -> lowest n.
        unsigned sel = 0;
        for (int k = 0; k < dk; ++k) {
            float bv = cl[0]; int bj = 0;
            #pragma unroll
            for (int j = 1; j < 15; ++j) {
                if (cl[j] < bv) { bv = cl[j]; bj = j; }
            }
            unsigned long long key =
                ((unsigned long long)__float_as_uint(bv) << 32) | (unsigned)(bj * 64 + t);
            key = dpp_min_u64(key);
            unsigned lo = (unsigned)__builtin_amdgcn_readlane((int)(unsigned)(key & 0xFFFFFFFFull), 63);
            int mn = (int)lo;
            bool win = ((mn & 63) == t);
            int slot = mn >> 6;
            if (win) sel |= 1u << slot;
            #pragma unroll
            for (int j = 0; j < 15; ++j) cl[j] = (win && slot == j) ? INFINITY : cl[j];
        }

        #pragma unroll
        for (int j = 0; j < 15; ++j) {
            int n = j * 64 + t;
            P.match0[bg * NN + n] = (unsigned char)((sel >> j) & 1u);
        }
    }

    grid.sync();

    // ================= P3: per (b, n) column resolve + outputs =================
    int gtid = (int)blockIdx.x * BLK + (int)threadIdx.x;
    for (int i = gtid; i < NB * NN; i += GRID * BLK) {
        int b = i / NN, n = i % NN;

        int cnt = 0, first = -1;
        unsigned mloc = 0;
        #pragma unroll
        for (int g = 0; g < NG; ++g) {
            int v = P.match0[(b * NG + g) * NN + n];
            if (v) {
                cnt++;
                mloc |= 1u << g;
                if (first < 0) first = g;
            }
        }

        int mgt, fg;
        if (cnt > 1) {
            float bv = INFINITY; int bgi = 0;
            #pragma unroll
            for (int g = 0; g < NG; ++g) {
                float c = P.ocost[(b * NG + g) * NN + n];
                if (c < bv) { bv = c; bgi = g; }
            }
            mloc = 1u << bgi;
            mgt = bgi;
            fg = 1;
        } else {
            mgt = (first >= 0) ? first : 0;
            fg = (cnt > 0) ? 1 : 0;
        }

        #pragma unroll
        for (int g = 0; g < NG; ++g) {
            P.om[(b * NG + g) * NN + n] = ((mloc >> g) & 1u) ? 1.0f : 0.0f;
        }
        P.ofg[b * NN + n] = fg ? 1.0f : 0.0f;
        P.omg[b * NN + n] = (float)mgt;
    }
}

extern "C" void kernel_launch(void* const* d_in, const int* in_sizes, int n_in,
                              void* d_out, int out_size, void* d_ws, size_t ws_size,
                              hipStream_t stream) {
    KParams P;
    P.p0 = (const float*)d_in[0];
    P.a0 = (const int*)d_in[1];
    P.gj0 = (const int*)d_in[2];
    P.gi0 = (const int*)d_in[3];
    P.p1 = (const float*)d_in[5];
    P.a1 = (const int*)d_in[6];
    P.gj1 = (const int*)d_in[7];
    P.gi1 = (const int*)d_in[8];
    P.p2 = (const float*)d_in[10];
    P.a2 = (const int*)d_in[11];
    P.gj2 = (const int*)d_in[12];
    P.gi2 = (const int*)d_in[13];
    P.tgt = (const float*)d_in[15];

    // Output layout (ALL float32, concatenated in return order):
    // matching (NB*NG*NN) | fg (NB*NN) | matched_gt (NB*NN) | cost (NB*NG*NN)
    float* o = (float*)d_out;
    P.om = o;
    P.ofg = o + (size_t)NB * NG * NN;
    P.omg = P.ofg + (size_t)NB * NN;
    P.ocost = P.omg + (size_t)NB * NN;

    // Workspace carve (8B-aligned first)
    char* w = (char*)d_ws;
    P.Ssum = (double*)w;            w += (size_t)NB * NN * sizeof(double);
    P.pbox = (float*)w;             w += (size_t)NB * NN * 4 * sizeof(float);
    P.pobj = (float*)w;             w += (size_t)NB * NN * sizeof(float);
    P.parea = (float*)w;            w += (size_t)NB * NN * sizeof(float);
    P.coff = (int*)w;               w += (size_t)NB * NN * sizeof(int);
    P.clvl = (int*)w;               w += (size_t)NB * NN * sizeof(int);
    P.match0 = (unsigned char*)w;   w += (size_t)NB * NG * NN;

    (void)in_sizes; (void)n_in; (void)out_size; (void)ws_size;

    void* args[] = { (void*)&P };
    hipLaunchCooperativeKernel((const void*)k_fused, dim3(GRID), dim3(BLK),
                               args, 0, stream);
}

// Round 6
// 156.581 us; speedup vs baseline: 1.0696x; 1.0696x over previous
//
#include <hip/hip_runtime.h>
#include <math.h>

#define NB 16
#define NG 32
#define NM 320
#define NN 960      // 3 * NM
#define NA 3
#define NCH 85
#define NC 80
#define NK 20
#define BLKT 1024   // 16 waves per block, one block per batch

// ---------------- DPP helpers ----------------
template<int CTRL>
__device__ __forceinline__ unsigned long long dpp_u64_self(unsigned long long x) {
    int lo = (int)(unsigned)(x & 0xFFFFFFFFull);
    int hi = (int)(unsigned)(x >> 32);
    int lo2 = __builtin_amdgcn_update_dpp(lo, lo, CTRL, 0xF, 0xF, false);
    int hi2 = __builtin_amdgcn_update_dpp(hi, hi, CTRL, 0xF, 0xF, false);
    return ((unsigned long long)(unsigned)hi2 << 32) | (unsigned)lo2;
}

// max-reduce of u64 keys across 64 lanes; result valid in lane 63
__device__ __forceinline__ unsigned long long dpp_max_u64(unsigned long long x) {
    unsigned long long o;
    o = dpp_u64_self<0x111>(x); x = (o > x) ? o : x;   // row_shr:1
    o = dpp_u64_self<0x112>(x); x = (o > x) ? o : x;   // row_shr:2
    o = dpp_u64_self<0x114>(x); x = (o > x) ? o : x;   // row_shr:4
    o = dpp_u64_self<0x118>(x); x = (o > x) ? o : x;   // row_shr:8
    o = dpp_u64_self<0x142>(x); x = (o > x) ? o : x;   // row_bcast:15
    o = dpp_u64_self<0x143>(x); x = (o > x) ? o : x;   // row_bcast:31
    return x;
}

__device__ __forceinline__ unsigned long long dpp_min_u64(unsigned long long x) {
    unsigned long long o;
    o = dpp_u64_self<0x111>(x); x = (o < x) ? o : x;
    o = dpp_u64_self<0x112>(x); x = (o < x) ? o : x;
    o = dpp_u64_self<0x114>(x); x = (o < x) ? o : x;
    o = dpp_u64_self<0x118>(x); x = (o < x) ? o : x;
    o = dpp_u64_self<0x142>(x); x = (o < x) ? o : x;
    o = dpp_u64_self<0x143>(x); x = (o < x) ? o : x;
    return x;
}

// f64 shifted-add term (bound_ctrl=1: out-of-row lanes contribute +0.0)
template<int CTRL>
__device__ __forceinline__ double dpp_f64_zero(double x) {
    long long b = __double_as_longlong(x);
    int lo = (int)(unsigned)((unsigned long long)b & 0xFFFFFFFFull);
    int hi = (int)(unsigned)((unsigned long long)b >> 32);
    int lo2 = __builtin_amdgcn_update_dpp(0, lo, CTRL, 0xF, 0xF, true);
    int hi2 = __builtin_amdgcn_update_dpp(0, hi, CTRL, 0xF, 0xF, true);
    unsigned long long r = ((unsigned long long)(unsigned)hi2 << 32) | (unsigned)lo2;
    return __longlong_as_double((long long)r);
}

struct KParams {
    const float *p0, *p1, *p2, *tgt;
    const int *a0, *gj0, *gi0, *a1, *gj1, *gi1, *a2, *gj2, *gi2;
    float *om, *ofg, *omg, *ocost;
};

__global__ __launch_bounds__(BLKT) void k_fused(KParams P)
{
    // ---- LDS (~42 KB) ----
    __shared__ int    s_off[NN];
    __shared__ int    s_lvl[NN];
    __shared__ float  s_pobj[NN], s_parea[NN];
    __shared__ float  s_x1[NN], s_y1[NN], s_x2[NN], s_y2[NN];
    __shared__ double s_S[NN];
    __shared__ unsigned long long s_mb[NG * 15];   // match bitmask: bit n of row g

    int b = (int)blockIdx.x;          // one block per batch
    int t = (int)threadIdx.x;
    int lane = t & 63;
    int w = t >> 6;                   // wave id 0..15

    // ================= P1a: per-candidate meta (threads 0..959) =================
    if (t < NN) {
        int n = t;
        int lvl = (n < NM) ? 0 : ((n < 2 * NM) ? 1 : 2);
        int m = n - lvl * NM;

        const int* pa = (lvl == 0) ? P.a0 : ((lvl == 1) ? P.a1 : P.a2);
        const int* pj = (lvl == 0) ? P.gj0 : ((lvl == 1) ? P.gj1 : P.gj2);
        const int* pi = (lvl == 0) ? P.gi0 : ((lvl == 1) ? P.gi1 : P.gi2);
        const float* pr = (lvl == 0) ? P.p0 : ((lvl == 1) ? P.p1 : P.p2);
        int h = (lvl == 0) ? 80 : ((lvl == 1) ? 40 : 20);
        float s = (lvl == 0) ? 8.0f : ((lvl == 1) ? 16.0f : 32.0f);

        int aa = pa[b * NM + m];
        int jj = pj[b * NM + m];
        int ii = pi[b * NM + m];
        int off = (((b * NA + aa) * h + jj) * h + ii) * NCH;
        const float* c = pr + off;

        float cx = c[0] * s, cy = c[1] * s, ww = c[2] * s, hh = c[3] * s;
        float x1 = cx - ww * 0.5f, y1 = cy - hh * 0.5f;
        float x2 = cx + ww * 0.5f, y2 = cy + hh * 0.5f;

        s_off[n] = off;
        s_lvl[n] = lvl;
        s_pobj[n] = c[4];
        s_parea[n] = (x2 - x1) * (y2 - y1);
        s_x1[n] = x1; s_y1[n] = y1; s_x2[n] = x2; s_y2[n] = y2;
    }
    __syncthreads();

    // ================= P1b: class sums — 16-lane subgroup per candidate =================
    {
        int sub = t >> 4;         // subgroup 0..63 within block
        int l16 = t & 15;
        for (int pass = 0; pass < 15; ++pass) {
            int n = pass * 64 + sub;
            int lvl = s_lvl[n];
            const float* c = ((lvl == 0) ? P.p0 : ((lvl == 1) ? P.p1 : P.p2)) + s_off[n];
            float po = s_pobj[n];
            double S = 0.0;
            #pragma unroll
            for (int q = 0; q < 5; ++q) {
                float pc = c[5 + l16 + 16 * q];
                float y = sqrtf(pc * po);
                float z = logf(y / (1.0f - y));
                float sp = fmaxf(z, 0.0f) + log1pf(expf(-fabsf(z)));
                S += (double)sp;
            }
            // reduce within 16-lane row; total lands in l16==15
            S += dpp_f64_zero<0x111>(S);
            S += dpp_f64_zero<0x112>(S);
            S += dpp_f64_zero<0x114>(S);
            S += dpp_f64_zero<0x118>(S);
            if (l16 == 15) s_S[n] = S;
        }
    }
    __syncthreads();

    // ================= P2: 2 rows (b,g) per wave =================
    for (int rr = 0; rr < 2; ++rr) {
        int g = w * 2 + rr;
        int bg = b * NG + g;

        const float* tg = P.tgt + bg * 6;
        int cls = (int)tg[1];
        float gcx = tg[2] * 640.0f, gcy = tg[3] * 640.0f;
        float gw_ = tg[4] * 640.0f, gh = tg[5] * 640.0f;
        float gx1 = gcx - gw_ * 0.5f, gy1 = gcy - gh * 0.5f;
        float gx2 = gcx + gw_ * 0.5f, gy2 = gcy + gh * 0.5f;
        float ga = (gx2 - gx1) * (gy2 - gy1);

        float cl[15], io[15];
        #pragma unroll
        for (int j = 0; j < 15; ++j) {
            int n = j * 64 + lane;
            int lvl = s_lvl[n];
            const float* pr = (lvl == 0) ? P.p0 : ((lvl == 1) ? P.p1 : P.p2);
            float pc = pr[s_off[n] + 5 + cls];
            float po = s_pobj[n];
            float y = sqrtf(pc * po);
            float z = logf(y / (1.0f - y));
            float clsl = (float)(s_S[n] - (double)z);

            float lx = fmaxf(gx1, s_x1[n]), ly = fmaxf(gy1, s_y1[n]);
            float rx = fminf(gx2, s_x2[n]), ry = fminf(gy2, s_y2[n]);
            float wx = fmaxf(rx - lx, 0.0f), wy = fmaxf(ry - ly, 0.0f);
            float inter = wx * wy;
            float iou = inter / (ga + s_parea[n] - inter);
            float il = -logf(iou + 1e-5f);
            float cst = clsl + 3.0f * il;

            cl[j] = cst;
            io[j] = iou;
            P.ocost[bg * NN + n] = cst;
        }

        // ---- dk: sum of top-20 iou (iou >= 0, bits order-monotonic; tie -> lowest n)
        double ssum = 0.0;
        for (int k = 0; k < NK; ++k) {
            float bv = io[0]; int bj = 0;
            #pragma unroll
            for (int j = 1; j < 15; ++j) {
                if (io[j] > bv) { bv = io[j]; bj = j; }
            }
            unsigned long long key =
                ((unsigned long long)__float_as_uint(bv) << 32) | (unsigned)(~(unsigned)(bj * 64 + lane));
            key = dpp_max_u64(key);
            unsigned lo = (unsigned)__builtin_amdgcn_readlane((int)(unsigned)(key & 0xFFFFFFFFull), 63);
            unsigned hi = (unsigned)__builtin_amdgcn_readlane((int)(unsigned)(key >> 32), 63);
            float mval = __uint_as_float(hi);
            int mn = (int)(~lo);
            ssum += (double)mval;
            bool win = ((mn & 63) == lane);
            int slot = mn >> 6;
            #pragma unroll
            for (int j = 0; j < 15; ++j) io[j] = (win && slot == j) ? -2.0f : io[j];
        }
        int dk = (int)((float)ssum);
        if (dk < 1) dk = 1;
        if (dk > NK) dk = NK;

        // ---- select dk smallest costs (tie -> lowest n)
        unsigned sel = 0;
        for (int k = 0; k < dk; ++k) {
            float bv = cl[0]; int bj = 0;
            #pragma unroll
            for (int j = 1; j < 15; ++j) {
                if (cl[j] < bv) { bv = cl[j]; bj = j; }
            }
            unsigned long long key =
                ((unsigned long long)__float_as_uint(bv) << 32) | (unsigned)(bj * 64 + lane);
            key = dpp_min_u64(key);
            unsigned lo = (unsigned)__builtin_amdgcn_readlane((int)(unsigned)(key & 0xFFFFFFFFull), 63);
            int mn = (int)lo;
            bool win = ((mn & 63) == lane);
            int slot = mn >> 6;
            if (win) sel |= 1u << slot;
            #pragma unroll
            for (int j = 0; j < 15; ++j) cl[j] = (win && slot == j) ? INFINITY : cl[j];
        }

        #pragma unroll
        for (int j = 0; j < 15; ++j) {
            unsigned long long mask = __ballot((sel >> j) & 1u);
            if (lane == 0) s_mb[g * 15 + j] = mask;
        }
    }
    __syncthreads();

    // ================= P3: per-column resolve + outputs (threads 0..959) =================
    if (t < NN) {
        int n = t;
        int word = n >> 6;
        int bit = n & 63;

        int cnt = 0, first = -1;
        unsigned mloc = 0;
        #pragma unroll
        for (int g = 0; g < NG; ++g) {
            unsigned v = (unsigned)((s_mb[g * 15 + word] >> bit) & 1ull);
            cnt += (int)v;
            mloc |= v << g;
            if (v && first < 0) first = g;
        }

        int mgt, fg;
        if (cnt > 1) {
            float bv = INFINITY; int bgi = 0;
            #pragma unroll
            for (int g = 0; g < NG; ++g) {
                float c = P.ocost[(b * NG + g) * NN + n];
                if (c < bv) { bv = c; bgi = g; }
            }
            mloc = 1u << bgi;
            mgt = bgi;
            fg = 1;
        } else {
            mgt = (first >= 0) ? first : 0;
            fg = (cnt > 0) ? 1 : 0;
        }

        #pragma unroll
        for (int g = 0; g < NG; ++g) {
            P.om[(b * NG + g) * NN + n] = ((mloc >> g) & 1u) ? 1.0f : 0.0f;
        }
        P.ofg[b * NN + n] = fg ? 1.0f : 0.0f;
        P.omg[b * NN + n] = (float)mgt;
    }
}

extern "C" void kernel_launch(void* const* d_in, const int* in_sizes, int n_in,
                              void* d_out, int out_size, void* d_ws, size_t ws_size,
                              hipStream_t stream) {
    KParams P;
    P.p0 = (const float*)d_in[0];
    P.a0 = (const int*)d_in[1];
    P.gj0 = (const int*)d_in[2];
    P.gi0 = (const int*)d_in[3];
    P.p1 = (const float*)d_in[5];
    P.a1 = (const int*)d_in[6];
    P.gj1 = (const int*)d_in[7];
    P.gi1 = (const int*)d_in[8];
    P.p2 = (const float*)d_in[10];
    P.a2 = (const int*)d_in[11];
    P.gj2 = (const int*)d_in[12];
    P.gi2 = (const int*)d_in[13];
    P.tgt = (const float*)d_in[15];

    // Output layout (ALL float32, concatenated in return order):
    // matching (NB*NG*NN) | fg (NB*NN) | matched_gt (NB*NN) | cost (NB*NG*NN)
    float* o = (float*)d_out;
    P.om = o;
    P.ofg = o + (size_t)NB * NG * NN;
    P.omg = P.ofg + (size_t)NB * NN;
    P.ocost = P.omg + (size_t)NB * NN;

    (void)in_sizes; (void)n_in; (void)out_size; (void)d_ws; (void)ws_size;

    k_fused<<<NB, BLKT, 0, stream>>>(P);
}

// Round 7
// 82.591 us; speedup vs baseline: 2.0278x; 1.8958x over previous
//
#include <hip/hip_runtime.h>
#include <math.h>

#define NB 16
#define NG 32
#define NM 320
#define NN 960      // 3 * NM
#define NA 3
#define NCH 85
#define NC 80
#define NK 20

// ---------------- DPP wave-reduce helpers ----------------
template<int CTRL>
__device__ __forceinline__ unsigned long long dpp_u64_self(unsigned long long x) {
    int lo = (int)(unsigned)(x & 0xFFFFFFFFull);
    int hi = (int)(unsigned)(x >> 32);
    int lo2 = __builtin_amdgcn_update_dpp(lo, lo, CTRL, 0xF, 0xF, false);
    int hi2 = __builtin_amdgcn_update_dpp(hi, hi, CTRL, 0xF, 0xF, false);
    return ((unsigned long long)(unsigned)hi2 << 32) | (unsigned)lo2;
}

// max-reduce of u64 keys; result valid in lane 63
__device__ __forceinline__ unsigned long long dpp_max_u64(unsigned long long x) {
    unsigned long long o;
    o = dpp_u64_self<0x111>(x); x = (o > x) ? o : x;   // row_shr:1
    o = dpp_u64_self<0x112>(x); x = (o > x) ? o : x;   // row_shr:2
    o = dpp_u64_self<0x114>(x); x = (o > x) ? o : x;   // row_shr:4
    o = dpp_u64_self<0x118>(x); x = (o > x) ? o : x;   // row_shr:8
    o = dpp_u64_self<0x142>(x); x = (o > x) ? o : x;   // row_bcast:15
    o = dpp_u64_self<0x143>(x); x = (o > x) ? o : x;   // row_bcast:31
    return x;
}

__device__ __forceinline__ unsigned long long dpp_min_u64(unsigned long long x) {
    unsigned long long o;
    o = dpp_u64_self<0x111>(x); x = (o < x) ? o : x;
    o = dpp_u64_self<0x112>(x); x = (o < x) ? o : x;
    o = dpp_u64_self<0x114>(x); x = (o < x) ? o : x;
    o = dpp_u64_self<0x118>(x); x = (o < x) ? o : x;
    o = dpp_u64_self<0x142>(x); x = (o < x) ? o : x;
    o = dpp_u64_self<0x143>(x); x = (o < x) ? o : x;
    return x;
}

// f64 add-reduce (bound_ctrl=1: invalid lanes contribute +0.0); result valid in lane 63
template<int CTRL>
__device__ __forceinline__ double dpp_f64_zero(double x) {
    long long b = __double_as_longlong(x);
    int lo = (int)(unsigned)((unsigned long long)b & 0xFFFFFFFFull);
    int hi = (int)(unsigned)((unsigned long long)b >> 32);
    int lo2 = __builtin_amdgcn_update_dpp(0, lo, CTRL, 0xF, 0xF, true);
    int hi2 = __builtin_amdgcn_update_dpp(0, hi, CTRL, 0xF, 0xF, true);
    unsigned long long r = ((unsigned long long)(unsigned)hi2 << 32) | (unsigned)lo2;
    return __longlong_as_double((long long)r);
}

__device__ __forceinline__ double dpp_sum_f64(double x) {
    x += dpp_f64_zero<0x111>(x);
    x += dpp_f64_zero<0x112>(x);
    x += dpp_f64_zero<0x114>(x);
    x += dpp_f64_zero<0x118>(x);
    x += dpp_f64_zero<0x142>(x);
    x += dpp_f64_zero<0x143>(x);
    return x;   // lane 63 holds the total
}

// ---------------- K1: per-candidate prep (one WAVE per candidate) ----------------
__global__ __launch_bounds__(256) void k_prep(
                       const float* __restrict__ p0, const float* __restrict__ p1, const float* __restrict__ p2,
                       const int* __restrict__ a0, const int* __restrict__ gj0, const int* __restrict__ gi0,
                       const int* __restrict__ a1, const int* __restrict__ gj1, const int* __restrict__ gi1,
                       const int* __restrict__ a2, const int* __restrict__ gj2, const int* __restrict__ gi2,
                       int* __restrict__ coff, int* __restrict__ clvl,
                       float* __restrict__ pobj, float* __restrict__ parea,
                       float* __restrict__ pbox, double* __restrict__ Ssum,
                       unsigned* __restrict__ done)
{
    // zero the per-batch completion counters for this replay
    if (blockIdx.x == 0 && threadIdx.x < NB) done[threadIdx.x] = 0;

    int wid = blockIdx.x * 4 + ((int)threadIdx.x >> 6);   // candidate index
    int lane = (int)threadIdx.x & 63;
    if (wid >= NB * NN) return;
    int b = wid / NN, n = wid % NN;
    int lvl = (n < NM) ? 0 : ((n < 2 * NM) ? 1 : 2);
    int m = n - lvl * NM;

    const int* pa = (lvl == 0) ? a0 : ((lvl == 1) ? a1 : a2);
    const int* pj = (lvl == 0) ? gj0 : ((lvl == 1) ? gj1 : gj2);
    const int* pi = (lvl == 0) ? gi0 : ((lvl == 1) ? gi1 : gi2);
    const float* pr = (lvl == 0) ? p0 : ((lvl == 1) ? p1 : p2);
    int h = (lvl == 0) ? 80 : ((lvl == 1) ? 40 : 20);
    float s = (lvl == 0) ? 8.0f : ((lvl == 1) ? 16.0f : 32.0f);

    int aa = pa[b * NM + m];
    int jj = pj[b * NM + m];
    int ii = pi[b * NM + m];
    int off = (((b * NA + aa) * h + jj) * h + ii) * NCH;
    const float* c = pr + off;

    float po = c[4];
    double S = 0.0;
    for (int cc = lane; cc < NC; cc += 64) {
        float pc = c[5 + cc];
        float y = sqrtf(pc * po);
        float z = logf(y / (1.0f - y));
        float sp = fmaxf(z, 0.0f) + log1pf(expf(-fabsf(z)));
        S += (double)sp;
    }
    S = dpp_sum_f64(S);   // valid in lane 63

    if (lane == 63) {
        float cx = c[0] * s, cy = c[1] * s, w = c[2] * s, hh = c[3] * s;
        float x1 = cx - w * 0.5f, y1 = cy - hh * 0.5f;
        float x2 = cx + w * 0.5f, y2 = cy + hh * 0.5f;

        coff[wid] = off;
        clvl[wid] = lvl;
        pobj[wid] = po;
        parea[wid] = (x2 - x1) * (y2 - y1);
        pbox[wid * 4 + 0] = x1;
        pbox[wid * 4 + 1] = y1;
        pbox[wid * 4 + 2] = x2;
        pbox[wid * 4 + 3] = y2;
        Ssum[wid] = S;
    }
}

// ---------------- K2: one wave per (b, g) row; last block of batch resolves ----------------
__global__ __launch_bounds__(64) void k_row(
        const float* __restrict__ p0, const float* __restrict__ p1, const float* __restrict__ p2,
        const float* __restrict__ tgt,
        const int* __restrict__ coff, const int* __restrict__ clvl,
        const float* __restrict__ pobj, const float* __restrict__ parea,
        const float* __restrict__ pbox, const double* __restrict__ Ssum,
        unsigned long long* __restrict__ mb, unsigned* __restrict__ done,
        float* __restrict__ ocost, float* __restrict__ om,
        float* __restrict__ ofg, float* __restrict__ omg)
{
    int bg = blockIdx.x;            // bg = b*NG + g
    int b = bg / NG;
    int t = (int)threadIdx.x;

    const float* tg = tgt + bg * 6;
    int cls = (int)tg[1];
    float gcx = tg[2] * 640.0f, gcy = tg[3] * 640.0f;
    float gw = tg[4] * 640.0f, gh = tg[5] * 640.0f;
    float gx1 = gcx - gw * 0.5f, gy1 = gcy - gh * 0.5f;
    float gx2 = gcx + gw * 0.5f, gy2 = gcy + gh * 0.5f;
    float ga = (gx2 - gx1) * (gy2 - gy1);

    float cl[15], io[15];
    #pragma unroll
    for (int j = 0; j < 15; ++j) {
        int n = j * 64 + t;
        int idx = b * NN + n;
        int lvl = clvl[idx];
        const float* pr = (lvl == 0) ? p0 : ((lvl == 1) ? p1 : p2);
        float pc = pr[coff[idx] + 5 + cls];
        float po = pobj[idx];
        float y = sqrtf(pc * po);
        float z = logf(y / (1.0f - y));
        float clsl = (float)(Ssum[idx] - (double)z);

        const float* pb = pbox + idx * 4;
        float lx = fmaxf(gx1, pb[0]), ly = fmaxf(gy1, pb[1]);
        float rx = fminf(gx2, pb[2]), ry = fminf(gy2, pb[3]);
        float wx = fmaxf(rx - lx, 0.0f), wy = fmaxf(ry - ly, 0.0f);
        float inter = wx * wy;
        float iou = inter / (ga + parea[idx] - inter);
        float il = -logf(iou + 1e-5f);
        float cst = clsl + 3.0f * il;

        cl[j] = cst;
        io[j] = iou;
        ocost[bg * NN + n] = cst;
    }

    // ---- dk: sum of top-20 iou. iou >= 0 so float bits are order-monotonic.
    double ssum = 0.0;
    for (int k = 0; k < NK; ++k) {
        float bv = io[0]; int bj = 0;
        #pragma unroll
        for (int j = 1; j < 15; ++j) {
            if (io[j] > bv) { bv = io[j]; bj = j; }
        }
        unsigned long long key =
            ((unsigned long long)__float_as_uint(bv) << 32) | (unsigned)(~(unsigned)(bj * 64 + t));
        key = dpp_max_u64(key);
        unsigned lo = (unsigned)__builtin_amdgcn_readlane((int)(unsigned)(key & 0xFFFFFFFFull), 63);
        unsigned hi = (unsigned)__builtin_amdgcn_readlane((int)(unsigned)(key >> 32), 63);
        float mval = __uint_as_float(hi);
        int mn = (int)(~lo);
        ssum += (double)mval;
        bool win = ((mn & 63) == t);
        int slot = mn >> 6;
        #pragma unroll
        for (int j = 0; j < 15; ++j) io[j] = (win && slot == j) ? -2.0f : io[j];
    }
    int dk = (int)((float)ssum);
    if (dk < 1) dk = 1;
    if (dk > NK) dk = NK;

    // ---- select dk smallest costs (cost > 0, bits monotonic), tie -> lowest n.
    unsigned sel = 0;
    for (int k = 0; k < dk; ++k) {
        float bv = cl[0]; int bj = 0;
        #pragma unroll
        for (int j = 1; j < 15; ++j) {
            if (cl[j] < bv) { bv = cl[j]; bj = j; }
        }
        unsigned long long key =
            ((unsigned long long)__float_as_uint(bv) << 32) | (unsigned)(bj * 64 + t);
        key = dpp_min_u64(key);
        unsigned lo = (unsigned)__builtin_amdgcn_readlane((int)(unsigned)(key & 0xFFFFFFFFull), 63);
        int mn = (int)lo;
        bool win = ((mn & 63) == t);
        int slot = mn >> 6;
        if (win) sel |= 1u << slot;
        #pragma unroll
        for (int j = 0; j < 15; ++j) cl[j] = (win && slot == j) ? INFINITY : cl[j];
    }

    // ---- publish this row's selection as a 960-bit mask (15 x u64)
    #pragma unroll
    for (int j = 0; j < 15; ++j) {
        unsigned long long m = __ballot((sel >> j) & 1u);
        if (t == 0) mb[bg * 15 + j] = m;
    }

    // ---- release + count; last finisher of this batch resolves its columns
    __threadfence();
    unsigned old = 0;
    if (t == 0) old = __hip_atomic_fetch_add(&done[b], 1u, __ATOMIC_ACQ_REL, __HIP_MEMORY_SCOPE_AGENT);
    old = (unsigned)__shfl((int)old, 0, 64);
    if (old == NG - 1) {
        __threadfence();   // acquire: see all rows' mb + ocost
        #pragma unroll 1
        for (int j = 0; j < 15; ++j) {
            int n = j * 64 + t;
            unsigned mloc = 0;
            #pragma unroll
            for (int g = 0; g < NG; ++g) {
                unsigned long long wg = mb[(b * NG + g) * 15 + j];   // lane-uniform address
                mloc |= (unsigned)((wg >> t) & 1ull) << g;
            }
            int cnt = __popc(mloc);
            int mgt, fg;
            if (cnt > 1) {
                float bv = INFINITY; int bgi = 0;
                #pragma unroll
                for (int g = 0; g < NG; ++g) {
                    float c = ocost[(b * NG + g) * NN + n];
                    if (c < bv) { bv = c; bgi = g; }
                }
                mloc = 1u << bgi;
                mgt = bgi;
                fg = 1;
            } else {
                mgt = (cnt > 0) ? (__ffs(mloc) - 1) : 0;
                fg = (cnt > 0) ? 1 : 0;
            }
            #pragma unroll
            for (int g = 0; g < NG; ++g) {
                om[(b * NG + g) * NN + n] = ((mloc >> g) & 1u) ? 1.0f : 0.0f;
            }
            ofg[b * NN + n] = fg ? 1.0f : 0.0f;
            omg[b * NN + n] = (float)mgt;
        }
    }
}

extern "C" void kernel_launch(void* const* d_in, const int* in_sizes, int n_in,
                              void* d_out, int out_size, void* d_ws, size_t ws_size,
                              hipStream_t stream) {
    const float* p0 = (const float*)d_in[0];
    const int* a0 = (const int*)d_in[1];
    const int* gj0 = (const int*)d_in[2];
    const int* gi0 = (const int*)d_in[3];
    const float* p1 = (const float*)d_in[5];
    const int* a1 = (const int*)d_in[6];
    const int* gj1 = (const int*)d_in[7];
    const int* gi1 = (const int*)d_in[8];
    const float* p2 = (const float*)d_in[10];
    const int* a2 = (const int*)d_in[11];
    const int* gj2 = (const int*)d_in[12];
    const int* gi2 = (const int*)d_in[13];
    const float* tgt = (const float*)d_in[15];

    // Output layout (ALL float32, concatenated in return order):
    // matching (NB*NG*NN) | fg (NB*NN) | matched_gt (NB*NN) | cost (NB*NG*NN)
    float* o = (float*)d_out;
    float* om = o;
    float* ofg = o + (size_t)NB * NG * NN;
    float* omg = ofg + (size_t)NB * NN;
    float* ocost = omg + (size_t)NB * NN;

    // Workspace carve (8B-aligned first)
    char* w = (char*)d_ws;
    double* Ssum = (double*)w;              w += (size_t)NB * NN * sizeof(double);
    unsigned long long* mb = (unsigned long long*)w;  w += (size_t)NB * NG * 15 * sizeof(unsigned long long);
    float* pbox = (float*)w;                w += (size_t)NB * NN * 4 * sizeof(float);
    float* pobj = (float*)w;                w += (size_t)NB * NN * sizeof(float);
    float* parea = (float*)w;               w += (size_t)NB * NN * sizeof(float);
    int* coff = (int*)w;                    w += (size_t)NB * NN * sizeof(int);
    int* clvl = (int*)w;                    w += (size_t)NB * NN * sizeof(int);
    unsigned* done = (unsigned*)w;          w += (size_t)NB * sizeof(unsigned);

    (void)in_sizes; (void)n_in; (void)out_size; (void)ws_size;

    int nWaves = NB * NN;                 // one wave per candidate
    k_prep<<<(nWaves + 3) / 4, 256, 0, stream>>>(
        p0, p1, p2, a0, gj0, gi0, a1, gj1, gi1, a2, gj2, gi2,
        coff, clvl, pobj, parea, pbox, Ssum, done);

    k_row<<<NB * NG, 64, 0, stream>>>(
        p0, p1, p2, tgt, coff, clvl, pobj, parea, pbox, Ssum,
        mb, done, ocost, om, ofg, omg);
}

// Round 8
// 69.750 us; speedup vs baseline: 2.4011x; 1.1841x over previous
//
#include <hip/hip_runtime.h>
#include <math.h>

#define NB 16
#define NG 32
#define NM 320
#define NN 960      // 3 * NM
#define NA 3
#define NCH 85
#define NC 80
#define NK 20

// ---------------- DPP wave-reduce helpers ----------------
template<int CTRL>
__device__ __forceinline__ unsigned long long dpp_u64_self(unsigned long long x) {
    int lo = (int)(unsigned)(x & 0xFFFFFFFFull);
    int hi = (int)(unsigned)(x >> 32);
    int lo2 = __builtin_amdgcn_update_dpp(lo, lo, CTRL, 0xF, 0xF, false);
    int hi2 = __builtin_amdgcn_update_dpp(hi, hi, CTRL, 0xF, 0xF, false);
    return ((unsigned long long)(unsigned)hi2 << 32) | (unsigned)lo2;
}

__device__ __forceinline__ unsigned long long dpp_max_u64(unsigned long long x) {
    unsigned long long o;
    o = dpp_u64_self<0x111>(x); x = (o > x) ? o : x;   // row_shr:1
    o = dpp_u64_self<0x112>(x); x = (o > x) ? o : x;   // row_shr:2
    o = dpp_u64_self<0x114>(x); x = (o > x) ? o : x;   // row_shr:4
    o = dpp_u64_self<0x118>(x); x = (o > x) ? o : x;   // row_shr:8
    o = dpp_u64_self<0x142>(x); x = (o > x) ? o : x;   // row_bcast:15
    o = dpp_u64_self<0x143>(x); x = (o > x) ? o : x;   // row_bcast:31
    return x;
}

__device__ __forceinline__ unsigned long long dpp_min_u64(unsigned long long x) {
    unsigned long long o;
    o = dpp_u64_self<0x111>(x); x = (o < x) ? o : x;
    o = dpp_u64_self<0x112>(x); x = (o < x) ? o : x;
    o = dpp_u64_self<0x114>(x); x = (o < x) ? o : x;
    o = dpp_u64_self<0x118>(x); x = (o < x) ? o : x;
    o = dpp_u64_self<0x142>(x); x = (o < x) ? o : x;
    o = dpp_u64_self<0x143>(x); x = (o < x) ? o : x;
    return x;
}

template<int CTRL>
__device__ __forceinline__ double dpp_f64_zero(double x) {
    long long b = __double_as_longlong(x);
    int lo = (int)(unsigned)((unsigned long long)b & 0xFFFFFFFFull);
    int hi = (int)(unsigned)((unsigned long long)b >> 32);
    int lo2 = __builtin_amdgcn_update_dpp(0, lo, CTRL, 0xF, 0xF, true);
    int hi2 = __builtin_amdgcn_update_dpp(0, hi, CTRL, 0xF, 0xF, true);
    unsigned long long r = ((unsigned long long)(unsigned)hi2 << 32) | (unsigned)lo2;
    return __longlong_as_double((long long)r);
}

__device__ __forceinline__ double dpp_sum_f64(double x) {
    x += dpp_f64_zero<0x111>(x);
    x += dpp_f64_zero<0x112>(x);
    x += dpp_f64_zero<0x114>(x);
    x += dpp_f64_zero<0x118>(x);
    x += dpp_f64_zero<0x142>(x);
    x += dpp_f64_zero<0x143>(x);
    return x;   // lane 63 holds the total
}

// ---------------- K1: per-candidate prep (one WAVE per candidate) ----------------
// Outputs packed: pm1 = {x1,y1,x2,y2}; pm2 = {pobj, parea, bits(off), bits(lvl)}; Ssum f64.
__global__ __launch_bounds__(256) void k_prep(
                       const float* __restrict__ p0, const float* __restrict__ p1, const float* __restrict__ p2,
                       const int* __restrict__ a0, const int* __restrict__ gj0, const int* __restrict__ gi0,
                       const int* __restrict__ a1, const int* __restrict__ gj1, const int* __restrict__ gi1,
                       const int* __restrict__ a2, const int* __restrict__ gj2, const int* __restrict__ gi2,
                       float4* __restrict__ pm1, float4* __restrict__ pm2,
                       double* __restrict__ Ssum, unsigned* __restrict__ done)
{
    // zero the per-batch completion counters for this replay
    if (blockIdx.x == 0 && threadIdx.x < NB) done[threadIdx.x] = 0;

    int wid = blockIdx.x * 4 + ((int)threadIdx.x >> 6);   // candidate index
    int lane = (int)threadIdx.x & 63;
    if (wid >= NB * NN) return;
    int b = wid / NN, n = wid % NN;
    int lvl = (n < NM) ? 0 : ((n < 2 * NM) ? 1 : 2);
    int m = n - lvl * NM;

    const int* pa = (lvl == 0) ? a0 : ((lvl == 1) ? a1 : a2);
    const int* pj = (lvl == 0) ? gj0 : ((lvl == 1) ? gj1 : gj2);
    const int* pi = (lvl == 0) ? gi0 : ((lvl == 1) ? gi1 : gi2);
    const float* pr = (lvl == 0) ? p0 : ((lvl == 1) ? p1 : p2);
    int h = (lvl == 0) ? 80 : ((lvl == 1) ? 40 : 20);
    float s = (lvl == 0) ? 8.0f : ((lvl == 1) ? 16.0f : 32.0f);

    int aa = pa[b * NM + m];
    int jj = pj[b * NM + m];
    int ii = pi[b * NM + m];
    int off = (((b * NA + aa) * h + jj) * h + ii) * NCH;
    const float* c = pr + off;

    float po = c[4];
    double S = 0.0;
    for (int cc = lane; cc < NC; cc += 64) {
        float pc = c[5 + cc];
        float y = sqrtf(pc * po);
        float z = logf(y / (1.0f - y));
        float sp = fmaxf(z, 0.0f) + log1pf(expf(-fabsf(z)));
        S += (double)sp;
    }
    S = dpp_sum_f64(S);   // valid in lane 63

    if (lane == 63) {
        float cx = c[0] * s, cy = c[1] * s, w = c[2] * s, hh = c[3] * s;
        float x1 = cx - w * 0.5f, y1 = cy - hh * 0.5f;
        float x2 = cx + w * 0.5f, y2 = cy + hh * 0.5f;

        pm1[wid] = make_float4(x1, y1, x2, y2);
        pm2[wid] = make_float4(po, (x2 - x1) * (y2 - y1),
                               __uint_as_float((unsigned)off), __uint_as_float((unsigned)lvl));
        Ssum[wid] = S;
    }
}

// ---------------- K2: one wave per (b, g) row + distributed spin-resolve ----------------
__global__ __launch_bounds__(64) void k_row(
        const float* __restrict__ p0, const float* __restrict__ p1, const float* __restrict__ p2,
        const float* __restrict__ tgt,
        const float4* __restrict__ pm1, const float4* __restrict__ pm2,
        const double* __restrict__ Ssum,
        unsigned long long* __restrict__ mb, unsigned* __restrict__ done,
        float* __restrict__ ocost, float* __restrict__ om,
        float* __restrict__ ofg, float* __restrict__ omg)
{
    int bg = blockIdx.x;            // bg = b*NG + g
    int b = bg / NG;
    int g = bg & (NG - 1);
    int t = (int)threadIdx.x;

    const float* tg = tgt + bg * 6;
    int cls = (int)tg[1];
    float gcx = tg[2] * 640.0f, gcy = tg[3] * 640.0f;
    float gw = tg[4] * 640.0f, gh = tg[5] * 640.0f;
    float gx1 = gcx - gw * 0.5f, gy1 = gcy - gh * 0.5f;
    float gx2 = gcx + gw * 0.5f, gy2 = gcy + gh * 0.5f;
    float ga = (gx2 - gx1) * (gy2 - gy1);

    float cl[15], io[15];
    #pragma unroll
    for (int j = 0; j < 15; ++j) {
        int n = j * 64 + t;
        int idx = b * NN + n;
        float4 m1 = pm1[idx];
        float4 m2 = pm2[idx];
        float po = m2.x;
        float area = m2.y;
        int off = (int)__float_as_uint(m2.z);
        int lvl = (int)__float_as_uint(m2.w);
        const float* pr = (lvl == 0) ? p0 : ((lvl == 1) ? p1 : p2);
        float pc = pr[off + 5 + cls];
        float y = sqrtf(pc * po);
        float z = logf(y / (1.0f - y));
        float clsl = (float)(Ssum[idx] - (double)z);

        float lx = fmaxf(gx1, m1.x), ly = fmaxf(gy1, m1.y);
        float rx = fminf(gx2, m1.z), ry = fminf(gy2, m1.w);
        float wx = fmaxf(rx - lx, 0.0f), wy = fmaxf(ry - ly, 0.0f);
        float inter = wx * wy;
        float iou = inter / (ga + area - inter);
        float il = -logf(iou + 1e-5f);
        float cst = clsl + 3.0f * il;

        cl[j] = cst;
        io[j] = iou;
        ocost[bg * NN + n] = cst;
    }

    // ---- dk: sum of top-20 iou. iou >= 0 so float bits are order-monotonic.
    double ssum = 0.0;
    for (int k = 0; k < NK; ++k) {
        float bv = io[0]; int bj = 0;
        #pragma unroll
        for (int j = 1; j < 15; ++j) {
            if (io[j] > bv) { bv = io[j]; bj = j; }
        }
        unsigned long long key =
            ((unsigned long long)__float_as_uint(bv) << 32) | (unsigned)(~(unsigned)(bj * 64 + t));
        key = dpp_max_u64(key);
        unsigned lo = (unsigned)__builtin_amdgcn_readlane((int)(unsigned)(key & 0xFFFFFFFFull), 63);
        unsigned hi = (unsigned)__builtin_amdgcn_readlane((int)(unsigned)(key >> 32), 63);
        float mval = __uint_as_float(hi);
        int mn = (int)(~lo);
        ssum += (double)mval;
        bool win = ((mn & 63) == t);
        int slot = mn >> 6;
        #pragma unroll
        for (int j = 0; j < 15; ++j) io[j] = (win && slot == j) ? -2.0f : io[j];
    }
    int dk = (int)((float)ssum);
    if (dk < 1) dk = 1;
    if (dk > NK) dk = NK;

    // ---- select dk smallest costs (cost > 0, bits monotonic), tie -> lowest n.
    unsigned sel = 0;
    for (int k = 0; k < dk; ++k) {
        float bv = cl[0]; int bj = 0;
        #pragma unroll
        for (int j = 1; j < 15; ++j) {
            if (cl[j] < bv) { bv = cl[j]; bj = j; }
        }
        unsigned long long key =
            ((unsigned long long)__float_as_uint(bv) << 32) | (unsigned)(bj * 64 + t);
        key = dpp_min_u64(key);
        unsigned lo = (unsigned)__builtin_amdgcn_readlane((int)(unsigned)(key & 0xFFFFFFFFull), 63);
        int mn = (int)lo;
        bool win = ((mn & 63) == t);
        int slot = mn >> 6;
        if (win) sel |= 1u << slot;
        #pragma unroll
        for (int j = 0; j < 15; ++j) cl[j] = (win && slot == j) ? INFINITY : cl[j];
    }

    // ---- publish this row's selection as a 960-bit mask (15 x u64)
    #pragma unroll
    for (int j = 0; j < 15; ++j) {
        unsigned long long m = __ballot((sel >> j) & 1u);
        if (t == 0) mb[bg * 15 + j] = m;
    }

    // ---- release + count
    __threadfence();
    if (t == 0) __hip_atomic_fetch_add(&done[b], 1u, __ATOMIC_ACQ_REL, __HIP_MEMORY_SCOPE_AGENT);

    // ---- blocks g<15 each resolve ONE 64-column word of this batch
    if (g < 15) {
        // spin until all 32 rows of batch b have published (all blocks co-resident: 512 1-wave blocks)
        while (__hip_atomic_load(&done[b], __ATOMIC_ACQUIRE, __HIP_MEMORY_SCOPE_AGENT) < NG) {
            __builtin_amdgcn_s_sleep(8);
        }

        int j = g;                 // word index
        int n = j * 64 + t;        // this lane's column

        unsigned mloc = 0;
        #pragma unroll
        for (int gg = 0; gg < NG; ++gg) {
            unsigned long long wg = mb[(b * NG + gg) * 15 + j];   // wave-uniform address
            mloc |= (unsigned)((wg >> t) & 1ull) << gg;
        }
        int cnt = __popc(mloc);

        int mgt, fg;
        if (cnt > 1) {
            float bv = INFINITY; int bgi = 0;
            #pragma unroll
            for (int gg = 0; gg < NG; ++gg) {
                float c = ocost[(b * NG + gg) * NN + n];
                if (c < bv) { bv = c; bgi = gg; }
            }
            mloc = 1u << bgi;
            mgt = bgi;
            fg = 1;
        } else {
            mgt = (cnt > 0) ? (__ffs(mloc) - 1) : 0;
            fg = (cnt > 0) ? 1 : 0;
        }

        #pragma unroll
        for (int gg = 0; gg < NG; ++gg) {
            om[(b * NG + gg) * NN + n] = ((mloc >> gg) & 1u) ? 1.0f : 0.0f;
        }
        ofg[b * NN + n] = fg ? 1.0f : 0.0f;
        omg[b * NN + n] = (float)mgt;
    }
}

extern "C" void kernel_launch(void* const* d_in, const int* in_sizes, int n_in,
                              void* d_out, int out_size, void* d_ws, size_t ws_size,
                              hipStream_t stream) {
    const float* p0 = (const float*)d_in[0];
    const int* a0 = (const int*)d_in[1];
    const int* gj0 = (const int*)d_in[2];
    const int* gi0 = (const int*)d_in[3];
    const float* p1 = (const float*)d_in[5];
    const int* a1 = (const int*)d_in[6];
    const int* gj1 = (const int*)d_in[7];
    const int* gi1 = (const int*)d_in[8];
    const float* p2 = (const float*)d_in[10];
    const int* a2 = (const int*)d_in[11];
    const int* gj2 = (const int*)d_in[12];
    const int* gi2 = (const int*)d_in[13];
    const float* tgt = (const float*)d_in[15];

    // Output layout (ALL float32, concatenated in return order):
    // matching (NB*NG*NN) | fg (NB*NN) | matched_gt (NB*NN) | cost (NB*NG*NN)
    float* o = (float*)d_out;
    float* om = o;
    float* ofg = o + (size_t)NB * NG * NN;
    float* omg = ofg + (size_t)NB * NN;
    float* ocost = omg + (size_t)NB * NN;

    // Workspace carve (16B-aligned first)
    char* w = (char*)d_ws;
    float4* pm1 = (float4*)w;               w += (size_t)NB * NN * sizeof(float4);
    float4* pm2 = (float4*)w;               w += (size_t)NB * NN * sizeof(float4);
    double* Ssum = (double*)w;              w += (size_t)NB * NN * sizeof(double);
    unsigned long long* mb = (unsigned long long*)w;  w += (size_t)NB * NG * 15 * sizeof(unsigned long long);
    unsigned* done = (unsigned*)w;          w += (size_t)NB * sizeof(unsigned);

    (void)in_sizes; (void)n_in; (void)out_size; (void)ws_size;

    int nWaves = NB * NN;                 // one wave per candidate
    k_prep<<<(nWaves + 3) / 4, 256, 0, stream>>>(
        p0, p1, p2, a0, gj0, gi0, a1, gj1, gi1, a2, gj2, gi2,
        pm1, pm2, Ssum, done);

    k_row<<<NB * NG, 64, 0, stream>>>(
        p0, p1, p2, tgt, pm1, pm2, Ssum,
        mb, done, ocost, om, ofg, omg);
}

// Round 9
// 52.060 us; speedup vs baseline: 3.2170x; 1.3398x over previous
//
#include <hip/hip_runtime.h>
#include <math.h>

#define NB 16
#define NG 32
#define NM 320
#define NN 960      // 3 * NM
#define NA 3
#define NCH 85
#define NC 80
#define NK 20

// ---------------- DPP wave-reduce helpers ----------------
template<int CTRL>
__device__ __forceinline__ unsigned long long dpp_u64_self(unsigned long long x) {
    int lo = (int)(unsigned)(x & 0xFFFFFFFFull);
    int hi = (int)(unsigned)(x >> 32);
    int lo2 = __builtin_amdgcn_update_dpp(lo, lo, CTRL, 0xF, 0xF, false);
    int hi2 = __builtin_amdgcn_update_dpp(hi, hi, CTRL, 0xF, 0xF, false);
    return ((unsigned long long)(unsigned)hi2 << 32) | (unsigned)lo2;
}

__device__ __forceinline__ unsigned long long dpp_max_u64(unsigned long long x) {
    unsigned long long o;
    o = dpp_u64_self<0x111>(x); x = (o > x) ? o : x;   // row_shr:1
    o = dpp_u64_self<0x112>(x); x = (o > x) ? o : x;   // row_shr:2
    o = dpp_u64_self<0x114>(x); x = (o > x) ? o : x;   // row_shr:4
    o = dpp_u64_self<0x118>(x); x = (o > x) ? o : x;   // row_shr:8
    o = dpp_u64_self<0x142>(x); x = (o > x) ? o : x;   // row_bcast:15
    o = dpp_u64_self<0x143>(x); x = (o > x) ? o : x;   // row_bcast:31
    return x;
}

__device__ __forceinline__ unsigned long long dpp_min_u64(unsigned long long x) {
    unsigned long long o;
    o = dpp_u64_self<0x111>(x); x = (o < x) ? o : x;
    o = dpp_u64_self<0x112>(x); x = (o < x) ? o : x;
    o = dpp_u64_self<0x114>(x); x = (o < x) ? o : x;
    o = dpp_u64_self<0x118>(x); x = (o < x) ? o : x;
    o = dpp_u64_self<0x142>(x); x = (o < x) ? o : x;
    o = dpp_u64_self<0x143>(x); x = (o < x) ? o : x;
    return x;
}

template<int CTRL>
__device__ __forceinline__ double dpp_f64_zero(double x) {
    long long b = __double_as_longlong(x);
    int lo = (int)(unsigned)((unsigned long long)b & 0xFFFFFFFFull);
    int hi = (int)(unsigned)((unsigned long long)b >> 32);
    int lo2 = __builtin_amdgcn_update_dpp(0, lo, CTRL, 0xF, 0xF, true);
    int hi2 = __builtin_amdgcn_update_dpp(0, hi, CTRL, 0xF, 0xF, true);
    unsigned long long r = ((unsigned long long)(unsigned)hi2 << 32) | (unsigned)lo2;
    return __longlong_as_double((long long)r);
}

__device__ __forceinline__ double dpp_sum_f64(double x) {
    x += dpp_f64_zero<0x111>(x);
    x += dpp_f64_zero<0x112>(x);
    x += dpp_f64_zero<0x114>(x);
    x += dpp_f64_zero<0x118>(x);
    x += dpp_f64_zero<0x142>(x);
    x += dpp_f64_zero<0x143>(x);
    return x;   // lane 63 holds the total
}

// ---------------- K1: per-candidate prep (one WAVE per candidate) ----------------
// Writes: pm1 = {x1,y1,x2,y2}; Ssum (f64); zT[b][c][n] = z_c (transposed, for
// coalesced reads in k_row).
__global__ __launch_bounds__(256) void k_prep(
                       const float* __restrict__ p0, const float* __restrict__ p1, const float* __restrict__ p2,
                       const int* __restrict__ a0, const int* __restrict__ gj0, const int* __restrict__ gi0,
                       const int* __restrict__ a1, const int* __restrict__ gj1, const int* __restrict__ gi1,
                       const int* __restrict__ a2, const int* __restrict__ gj2, const int* __restrict__ gi2,
                       float4* __restrict__ pm1, float* __restrict__ zT,
                       double* __restrict__ Ssum, unsigned* __restrict__ done)
{
    // zero the per-batch completion counters for this replay
    if (blockIdx.x == 0 && threadIdx.x < NB) done[threadIdx.x] = 0;

    int wid = blockIdx.x * 4 + ((int)threadIdx.x >> 6);   // candidate index
    int lane = (int)threadIdx.x & 63;
    if (wid >= NB * NN) return;
    int b = wid / NN, n = wid % NN;
    int lvl = (n < NM) ? 0 : ((n < 2 * NM) ? 1 : 2);
    int m = n - lvl * NM;

    const int* pa = (lvl == 0) ? a0 : ((lvl == 1) ? a1 : a2);
    const int* pj = (lvl == 0) ? gj0 : ((lvl == 1) ? gj1 : gj2);
    const int* pi = (lvl == 0) ? gi0 : ((lvl == 1) ? gi1 : gi2);
    const float* pr = (lvl == 0) ? p0 : ((lvl == 1) ? p1 : p2);
    int h = (lvl == 0) ? 80 : ((lvl == 1) ? 40 : 20);
    float s = (lvl == 0) ? 8.0f : ((lvl == 1) ? 16.0f : 32.0f);

    int aa = pa[b * NM + m];
    int jj = pj[b * NM + m];
    int ii = pi[b * NM + m];
    int off = (((b * NA + aa) * h + jj) * h + ii) * NCH;
    const float* c = pr + off;

    float po = c[4];
    double S = 0.0;
    for (int cc = lane; cc < NC; cc += 64) {
        float pc = c[5 + cc];
        float y = sqrtf(pc * po);
        float z = logf(y / (1.0f - y));
        float sp = fmaxf(z, 0.0f) + log1pf(expf(-fabsf(z)));
        S += (double)sp;
        zT[(b * NC + cc) * NN + n] = z;     // transposed store (scattered; fire-and-forget)
    }
    S = dpp_sum_f64(S);   // valid in lane 63

    if (lane == 63) {
        float cx = c[0] * s, cy = c[1] * s, w = c[2] * s, hh = c[3] * s;
        float x1 = cx - w * 0.5f, y1 = cy - hh * 0.5f;
        float x2 = cx + w * 0.5f, y2 = cy + hh * 0.5f;

        pm1[wid] = make_float4(x1, y1, x2, y2);
        Ssum[wid] = S;
    }
}

// ---------------- K2: one wave per (b, g) row + distributed spin-resolve ----------------
__global__ __launch_bounds__(64) void k_row(
        const float* __restrict__ tgt,
        const float4* __restrict__ pm1, const float* __restrict__ zT,
        const double* __restrict__ Ssum,
        unsigned long long* __restrict__ mb, unsigned* __restrict__ done,
        float* __restrict__ ocost, float* __restrict__ om,
        float* __restrict__ ofg, float* __restrict__ omg)
{
    int bg = blockIdx.x;            // bg = b*NG + g
    int b = bg / NG;
    int g = bg & (NG - 1);
    int t = (int)threadIdx.x;

    const float* tg = tgt + bg * 6;
    int cls = (int)tg[1];
    float gcx = tg[2] * 640.0f, gcy = tg[3] * 640.0f;
    float gw = tg[4] * 640.0f, gh = tg[5] * 640.0f;
    float gx1 = gcx - gw * 0.5f, gy1 = gcy - gh * 0.5f;
    float gx2 = gcx + gw * 0.5f, gy2 = gcy + gh * 0.5f;
    float ga = (gx2 - gx1) * (gy2 - gy1);

    const float* zrow = zT + (size_t)(b * NC + cls) * NN;   // dense slice for this row's class

    float cl[15], io[15];
    #pragma unroll
    for (int j = 0; j < 15; ++j) {
        int n = j * 64 + t;
        int idx = b * NN + n;
        float4 m1 = pm1[idx];
        float area = (m1.z - m1.x) * (m1.w - m1.y);   // same f32 ops as reference a2
        float z = zrow[n];                            // coalesced
        float clsl = (float)(Ssum[idx] - (double)z);

        float lx = fmaxf(gx1, m1.x), ly = fmaxf(gy1, m1.y);
        float rx = fminf(gx2, m1.z), ry = fminf(gy2, m1.w);
        float wx = fmaxf(rx - lx, 0.0f), wy = fmaxf(ry - ly, 0.0f);
        float inter = wx * wy;
        float iou = inter / (ga + area - inter);
        float il = -logf(iou + 1e-5f);
        float cst = clsl + 3.0f * il;

        cl[j] = cst;
        io[j] = iou;
        ocost[bg * NN + n] = cst;
    }

    // ---- dk: sum of top-20 iou. iou >= 0 so float bits are order-monotonic.
    double ssum = 0.0;
    for (int k = 0; k < NK; ++k) {
        float bv = io[0]; int bj = 0;
        #pragma unroll
        for (int j = 1; j < 15; ++j) {
            if (io[j] > bv) { bv = io[j]; bj = j; }
        }
        unsigned long long key =
            ((unsigned long long)__float_as_uint(bv) << 32) | (unsigned)(~(unsigned)(bj * 64 + t));
        key = dpp_max_u64(key);
        unsigned lo = (unsigned)__builtin_amdgcn_readlane((int)(unsigned)(key & 0xFFFFFFFFull), 63);
        unsigned hi = (unsigned)__builtin_amdgcn_readlane((int)(unsigned)(key >> 32), 63);
        float mval = __uint_as_float(hi);
        int mn = (int)(~lo);
        ssum += (double)mval;
        bool win = ((mn & 63) == t);
        int slot = mn >> 6;
        #pragma unroll
        for (int j = 0; j < 15; ++j) io[j] = (win && slot == j) ? -2.0f : io[j];
    }
    int dk = (int)((float)ssum);
    if (dk < 1) dk = 1;
    if (dk > NK) dk = NK;

    // ---- select dk smallest costs (cost > 0, bits monotonic), tie -> lowest n.
    unsigned sel = 0;
    for (int k = 0; k < dk; ++k) {
        float bv = cl[0]; int bj = 0;
        #pragma unroll
        for (int j = 1; j < 15; ++j) {
            if (cl[j] < bv) { bv = cl[j]; bj = j; }
        }
        unsigned long long key =
            ((unsigned long long)__float_as_uint(bv) << 32) | (unsigned)(bj * 64 + t);
        key = dpp_min_u64(key);
        unsigned lo = (unsigned)__builtin_amdgcn_readlane((int)(unsigned)(key & 0xFFFFFFFFull), 63);
        int mn = (int)lo;
        bool win = ((mn & 63) == t);
        int slot = mn >> 6;
        if (win) sel |= 1u << slot;
        #pragma unroll
        for (int j = 0; j < 15; ++j) cl[j] = (win && slot == j) ? INFINITY : cl[j];
    }

    // ---- publish this row's selection as a 960-bit mask (15 x u64)
    #pragma unroll
    for (int j = 0; j < 15; ++j) {
        unsigned long long m = __ballot((sel >> j) & 1u);
        if (t == 0) mb[bg * 15 + j] = m;
    }

    // ---- release + count
    __threadfence();
    if (t == 0) __hip_atomic_fetch_add(&done[b], 1u, __ATOMIC_ACQ_REL, __HIP_MEMORY_SCOPE_AGENT);

    // ---- blocks g<15 each resolve ONE 64-column word of this batch
    if (g < 15) {
        // spin until all 32 rows of batch b have published (all 512 1-wave blocks co-resident)
        while (__hip_atomic_load(&done[b], __ATOMIC_ACQUIRE, __HIP_MEMORY_SCOPE_AGENT) < NG) {
            __builtin_amdgcn_s_sleep(8);
        }

        int j = g;                 // word index
        int n = j * 64 + t;        // this lane's column

        unsigned mloc = 0;
        #pragma unroll
        for (int gg = 0; gg < NG; ++gg) {
            unsigned long long wg = mb[(b * NG + gg) * 15 + j];   // wave-uniform address
            mloc |= (unsigned)((wg >> t) & 1ull) << gg;
        }
        int cnt = __popc(mloc);

        int mgt, fg;
        if (cnt > 1) {
            float bv = INFINITY; int bgi = 0;
            #pragma unroll
            for (int gg = 0; gg < NG; ++gg) {
                float c = ocost[(b * NG + gg) * NN + n];
                if (c < bv) { bv = c; bgi = gg; }
            }
            mloc = 1u << bgi;
            mgt = bgi;
            fg = 1;
        } else {
            mgt = (cnt > 0) ? (__ffs(mloc) - 1) : 0;
            fg = (cnt > 0) ? 1 : 0;
        }

        #pragma unroll
        for (int gg = 0; gg < NG; ++gg) {
            om[(b * NG + gg) * NN + n] = ((mloc >> gg) & 1u) ? 1.0f : 0.0f;
        }
        ofg[b * NN + n] = fg ? 1.0f : 0.0f;
        omg[b * NN + n] = (float)mgt;
    }
}

extern "C" void kernel_launch(void* const* d_in, const int* in_sizes, int n_in,
                              void* d_out, int out_size, void* d_ws, size_t ws_size,
                              hipStream_t stream) {
    const float* p0 = (const float*)d_in[0];
    const int* a0 = (const int*)d_in[1];
    const int* gj0 = (const int*)d_in[2];
    const int* gi0 = (const int*)d_in[3];
    const float* p1 = (const float*)d_in[5];
    const int* a1 = (const int*)d_in[6];
    const int* gj1 = (const int*)d_in[7];
    const int* gi1 = (const int*)d_in[8];
    const float* p2 = (const float*)d_in[10];
    const int* a2 = (const int*)d_in[11];
    const int* gj2 = (const int*)d_in[12];
    const int* gi2 = (const int*)d_in[13];
    const float* tgt = (const float*)d_in[15];

    // Output layout (ALL float32, concatenated in return order):
    // matching (NB*NG*NN) | fg (NB*NN) | matched_gt (NB*NN) | cost (NB*NG*NN)
    float* o = (float*)d_out;
    float* om = o;
    float* ofg = o + (size_t)NB * NG * NN;
    float* omg = ofg + (size_t)NB * NN;
    float* ocost = omg + (size_t)NB * NN;

    // Workspace carve (16B-aligned first)
    char* w = (char*)d_ws;
    float4* pm1 = (float4*)w;               w += (size_t)NB * NN * sizeof(float4);
    float* zT = (float*)w;                  w += (size_t)NB * NC * NN * sizeof(float);
    double* Ssum = (double*)w;              w += (size_t)NB * NN * sizeof(double);
    unsigned long long* mb = (unsigned long long*)w;  w += (size_t)NB * NG * 15 * sizeof(unsigned long long);
    unsigned* done = (unsigned*)w;          w += (size_t)NB * sizeof(unsigned);

    (void)in_sizes; (void)n_in; (void)out_size; (void)ws_size;

    int nWaves = NB * NN;                 // one wave per candidate
    k_prep<<<(nWaves + 3) / 4, 256, 0, stream>>>(
        p0, p1, p2, a0, gj0, gi0, a1, gj1, gi1, a2, gj2, gi2,
        pm1, zT, Ssum, done);

    k_row<<<NB * NG, 64, 0, stream>>>(
        tgt, pm1, zT, Ssum,
        mb, done, ocost, om, ofg, omg);
}